// Round 17
// baseline (1463.356 us; speedup 1.0000x reference)
//
#include <hip/hip_runtime.h>
#include <cstdint>

#define BATCH 64
#define SEQ   1024
#define FEAT  16
#define HID   256
#define GATE  768    // 3*HID
#define TC    64     // time-chunk length
#define LASTC 15     // SEQ/TC - 1
#define NT    512    // block threads (8 waves)

#define XPLD  776    // xpLDS row stride in f16 (768 + 8 pad -> bank-shifted rows)
#define XP_OFF 0
#define HB_OFF 99328             // 64*776*2
#define MK_OFF 100352            // HB_OFF + 1024
#define AS_OFF 100416            // MK_OFF + 64, 16-aligned
#define SMEM_SZ 134208           // AS_OFF + 16*2112 (As 64x264 f16 = 33792)

typedef _Float16 f16x8 __attribute__((ext_vector_type(8)));
typedef float    f32x4 __attribute__((ext_vector_type(4)));

__device__ __forceinline__ float sigmoidf_(float x) { return 1.0f / (1.0f + __expf(-x)); }
__device__ __forceinline__ float tanhf_(float x)    { return 2.0f / (1.0f + __expf(-2.0f * x)) - 1.0f; }

// ---------------------------------------------------------------------------
// Pack a [HID][GATE] fp32 matrix (U or W1/W2) into MFMA B-fragments (f16).
// Fragment (ct, kt, lane): 8 f16 = M[kt*32 + (lane>>4)*8 + e][ct*16 + (lane&15)]
// at out[((ct*8 + kt)*64 + lane) * 4].  (Verified convention, rounds 5-16.)
// ---------------------------------------------------------------------------
__global__ __launch_bounds__(256) void k_packB(const float* __restrict__ U,
                                               float* __restrict__ Bfrag)
{
    const int tid = blockIdx.x * 256 + threadIdx.x;   // < 48*8*64
    const int ct   = tid >> 9;
    const int kt   = (tid >> 6) & 7;
    const int lane = tid & 63;
    const int g = lane >> 4, i = lane & 15;
    const int col = ct * 16 + i;
    const int k0  = kt * 32 + g * 8;
    union { f16x8 v; float4 f; } u;
#pragma unroll
    for (int e = 0; e < 8; ++e)
        u.v[e] = (_Float16)U[(size_t)(k0 + e) * GATE + col];
    *(float4*)(Bfrag + (size_t)tid * 4) = u.f;
}

// ---------------------------------------------------------------------------
struct Params {
    const int*   batch;
    const float *W0, *b0, *b1, *b2;
    const float *Bf0, *Bf1, *Bf2;   // packed U0,U1,U2
    const float *Wp1, *Wp2;         // packed W1,W2
    _Float16 *y0a, *y0b, *y1a, *y1b;// f16 y rings (parity by chunk)
    float *h0, *h1, *h2;
    float *out, *hfin;
};

// ---------------------------------------------------------------------------
// GRU body: broadcast-A MFMA + LDS-resident xp + LDS mask + LDS-only
// per-step barrier (lgkmcnt(0)+s_barrier keeps the y/out global stores
// un-drained across steps). One block = ONE batch element; 8 waves;
// wave w owns h-cols [32w,32w+32).  (R11-verified core, xp source = LDS.)
// ---------------------------------------------------------------------------
__device__ __forceinline__ void gru_body(
    char* smem, const float* __restrict__ Bfrag,
    const float* __restrict__ bb, const int* __restrict__ batch,
    _Float16* __restrict__ yout, float* __restrict__ fout, int obase,
    float* __restrict__ hfinal, float* __restrict__ hstate, int t0, int b)
{
    const _Float16* xpL = (const _Float16*)(smem + XP_OFF);
    _Float16 (*hbuf)[HID] = (_Float16 (*)[HID])(smem + HB_OFF);
    unsigned char* mkl = (unsigned char*)(smem + MK_OFF);

    const int T  = threadIdx.x;
    const int w  = T >> 6;
    const int l  = T & 63;
    const int g  = l >> 4;
    const int i  = l & 15;
    const int g1 = g & 1;
    const int c  = 32 * w + i + 16 * g1;   // this lane's gate/h column

    // ---- register-resident B fragments: 6 col-tiles x 8 k-tiles ----
    f16x8 Bf[6][8];
    {
        const int cts[6] = {2 * w, 16 + 2 * w, 32 + 2 * w,
                            2 * w + 1, 17 + 2 * w, 33 + 2 * w};
#pragma unroll
        for (int ci = 0; ci < 6; ++ci)
#pragma unroll
            for (int kt = 0; kt < 8; ++kt) {
                float4 v = *(const float4*)(Bfrag + ((size_t)(cts[ci] * 8 + kt) * 64 + l) * 4);
                Bf[ci][kt] = __builtin_bit_cast(f16x8, v);
            }
    }

    const float bh = bb[GATE + 2 * HID + c];   // recurrent bias, h gate only

    // ---- stage chunk mask (removes per-step global mask load) ----
    for (int idx = T; idx < TC; idx += NT)
        mkl[idx] = (unsigned char)(batch[((size_t)b * SEQ + t0 + idx) * FEAT + (FEAT - 1)] != -1);

    float hprev = (t0 == 0) ? 0.0f : hstate[b * HID + c];
    if (l < 32) hbuf[0][32 * w + l] = (_Float16)hprev;
    __syncthreads();   // orders prologue xpL writes + mask + h init

    for (int tl = 0; tl < TC; ++tl) {
        // xp reads from LDS; issued before the mfma chain, consumed after
        const _Float16 cxz = xpL[tl * XPLD + c];
        const _Float16 cxr = xpL[tl * XPLD + HID + c];
        const _Float16 cxh = xpL[tl * XPLD + 2 * HID + c];
        const int cmf = mkl[tl];

        const _Float16* rd = hbuf[tl & 1];

        f32x4 az0 = {0.f, 0.f, 0.f, 0.f}, ar0 = az0, ah0 = az0;
        f32x4 az1 = az0, ar1 = az0, ah1 = az0;
#pragma unroll
        for (int kt = 0; kt < 8; ++kt) {
            const f16x8 a = *(const f16x8*)(rd + kt * 32 + g * 8);  // 16-lane broadcast
            az0 = __builtin_amdgcn_mfma_f32_16x16x32_f16(a, Bf[0][kt], az0, 0, 0, 0);
            ar0 = __builtin_amdgcn_mfma_f32_16x16x32_f16(a, Bf[1][kt], ar0, 0, 0, 0);
            ah0 = __builtin_amdgcn_mfma_f32_16x16x32_f16(a, Bf[2][kt], ah0, 0, 0, 0);
            az1 = __builtin_amdgcn_mfma_f32_16x16x32_f16(a, Bf[3][kt], az1, 0, 0, 0);
            ar1 = __builtin_amdgcn_mfma_f32_16x16x32_f16(a, Bf[4][kt], ar1, 0, 0, 0);
            ah1 = __builtin_amdgcn_mfma_f32_16x16x32_f16(a, Bf[5][kt], ah1, 0, 0, 0);
        }

        const float az = g1 ? az1[0] : az0[0];
        const float ar = g1 ? ar1[0] : ar0[0];
        const float ah = g1 ? ah1[0] : ah0[0];

        const float z  = sigmoidf_((float)cxz + az);
        const float r  = sigmoidf_((float)cxr + ar);
        const float hh = tanhf_((float)cxh + r * (ah + bh));
        float hn = z * hprev + (1.0f - z) * hh;
        hn = cmf ? hn : hprev;
        hprev = hn;

        if (l < 32) {
            if (yout)
                yout[((size_t)b * TC + tl) * HID + 32 * w + l] = (_Float16)hn;
            else
                fout[((size_t)b * SEQ + obase + tl) * HID + 32 * w + l] = hn;
            hbuf[(tl & 1) ^ 1][32 * w + l] = (_Float16)hn;
        }
        // LDS-only barrier: global stores stay in flight across steps
        asm volatile("s_waitcnt lgkmcnt(0)\n\ts_barrier" ::: "memory");
    }

    if (l < 32) {
        hstate[b * HID + 32 * w + l] = hprev;
        if (hfinal) hfinal[b * HID + 32 * w + l] = hprev;
    }
}

// ---------------------------------------------------------------------------
// MFMA GEMM prologue, LDS output: xpL[row][0..768) = bias + Yc[mt*64+row] @ W.
// Yc rows staged once in As; wave w covers col-tiles ct = 6w..6w+5.
// Output written to xpLDS (padded stride XPLD -> rows land on shifted banks).
// ---------------------------------------------------------------------------
__device__ __forceinline__ void gemm_mfma_lds(
    char* smem, const _Float16* __restrict__ Yc, const float* __restrict__ Wp,
    const float* __restrict__ bb, int mt)
{
    _Float16 (*As)[264] = (_Float16 (*)[264])(smem + AS_OFF);   // 64 x 264
    _Float16* xpL = (_Float16*)(smem + XP_OFF);

    const int T = threadIdx.x;
    const int w = T >> 6;
    const int l = T & 63;
    const int g = l >> 4;
    const int i = l & 15;

    {
        const _Float16* src = Yc + (size_t)mt * TC * HID;
#pragma unroll
        for (int q = 0; q < 4; ++q) {
            const int ch  = T * 4 + q;          // 0..2047 chunks of 16B
            const int row = ch >> 5;
            const int ko  = (ch & 31) * 8;
            *(float4*)&As[row][ko] = *(const float4*)(src + (size_t)row * HID + ko);
        }
    }
    __syncthreads();

    f16x8 Af[4][8];
#pragma unroll
    for (int rt = 0; rt < 4; ++rt)
#pragma unroll
        for (int kt = 0; kt < 8; ++kt)
            Af[rt][kt] = *(const f16x8*)&As[rt * 16 + i][kt * 32 + g * 8];

#pragma unroll
    for (int ci = 0; ci < 6; ++ci) {
        const int ct = w * 6 + ci;
        f16x8 Bfr[8];
#pragma unroll
        for (int kt = 0; kt < 8; ++kt) {
            float4 v = *(const float4*)(Wp + ((size_t)(ct * 8 + kt) * 64 + l) * 4);
            Bfr[kt] = __builtin_bit_cast(f16x8, v);
        }
        f32x4 acc[4];
#pragma unroll
        for (int rt = 0; rt < 4; ++rt) acc[rt] = (f32x4){0.f, 0.f, 0.f, 0.f};
#pragma unroll
        for (int kt = 0; kt < 8; ++kt) {
            acc[0] = __builtin_amdgcn_mfma_f32_16x16x32_f16(Af[0][kt], Bfr[kt], acc[0], 0, 0, 0);
            acc[1] = __builtin_amdgcn_mfma_f32_16x16x32_f16(Af[1][kt], Bfr[kt], acc[1], 0, 0, 0);
            acc[2] = __builtin_amdgcn_mfma_f32_16x16x32_f16(Af[2][kt], Bfr[kt], acc[2], 0, 0, 0);
            acc[3] = __builtin_amdgcn_mfma_f32_16x16x32_f16(Af[3][kt], Bfr[kt], acc[3], 0, 0, 0);
        }
        const int n = ct * 16 + i;
        const float bias = bb[n] + ((n < 2 * HID) ? bb[GATE + n] : 0.0f);
#pragma unroll
        for (int rt = 0; rt < 4; ++rt)
#pragma unroll
            for (int r = 0; r < 4; ++r)
                xpL[(rt * 16 + 4 * g + r) * XPLD + n] = (_Float16)(acc[rt][r] + bias);
    }
    // no trailing sync needed: gru_body's initial __syncthreads orders xpL
}

// ---------------------------------------------------------------------------
// Layer-0 projection prologue, LDS output (batch chunk staged in As region,
// W0 columns in registers).
// ---------------------------------------------------------------------------
__device__ __forceinline__ void xp0_lds(
    char* smem, const int* __restrict__ batch, const float* __restrict__ W0,
    const float* __restrict__ bb, int t0, int b)
{
    int* bl = (int*)(smem + AS_OFF);   // [TC][FEAT] = 4KB
    _Float16* xpL = (_Float16*)(smem + XP_OFF);
    const int T = threadIdx.x;
    for (int idx = T; idx < TC * FEAT; idx += NT)
        bl[idx] = batch[((size_t)b * SEQ + t0 + (idx >> 4)) * FEAT + (idx & 15)];
    __syncthreads();

    const int cc0 = T;            // 0..511
    const int cc1 = T + NT;       // 512..1023, valid if < GATE (T < 256)
    const bool two = (cc1 < GATE);

    float w0a[FEAT], w0b[FEAT];
#pragma unroll
    for (int f = 0; f < FEAT; ++f) w0a[f] = W0[f * GATE + cc0];
    if (two) {
#pragma unroll
        for (int f = 0; f < FEAT; ++f) w0b[f] = W0[f * GATE + cc1];
    }
    const float ba = bb[cc0] + ((cc0 < 2 * HID) ? bb[GATE + cc0] : 0.0f);
    const float bc = two ? (bb[cc1] + ((cc1 < 2 * HID) ? bb[GATE + cc1] : 0.0f)) : 0.0f;

    for (int tl = 0; tl < TC; ++tl) {
        float a0 = ba, a1 = bc;
#pragma unroll
        for (int f = 0; f < FEAT; ++f) {
            const float xf = (float)bl[tl * FEAT + f];   // LDS broadcast
            a0 += xf * w0a[f];
            if (two) a1 += xf * w0b[f];
        }
        xpL[tl * XPLD + cc0] = (_Float16)a0;
        if (two) xpL[tl * XPLD + cc1] = (_Float16)a1;
    }
    // gru_body's initial __syncthreads orders these LDS writes
}

// ---------------------------------------------------------------------------
// Fused pipeline kernel, 192 blocks (1 per CU), LAG-1 pipeline with
// LDS-resident xp: every gru block computes its own xp tile as a prologue.
// Launch d (0 .. LASTC+2):
//   bid   0- 63 : [xp0(chunk d) -> LDS] + gru layer0 chunk d
//   bid  64-127 : [gemm1(mt=b) from y0(d-1) -> LDS] + gru layer1 chunk d-1
//   bid 128-191 : [gemm2(mt=b) from y1(d-2) -> LDS] + gru layer2 chunk d-2
// Ring parity: y0 written @ d&1 (gru0), read next launch @ same parity;
// y1 written @ (d-1)&1 (gru1), read next launch @ same parity — writer and
// reader always in different launches, opposite buffer within a launch.
// ---------------------------------------------------------------------------
__global__ __launch_bounds__(NT, 1) void k_fused(Params P, int d)
{
    __shared__ __align__(16) char smem[SMEM_SZ];
    const int bid = blockIdx.x;

    if (bid < 64) {
        const int c = d;
        const int b = bid;
        if (c >= 0 && c <= LASTC) {
            xp0_lds(smem, P.batch, P.W0, P.b0, c * TC, b);
            gru_body(smem, P.Bf0, P.b0, P.batch,
                     (c & 1) ? P.y0b : P.y0a, nullptr, 0, nullptr, P.h0,
                     c * TC, b);
        }
    } else if (bid < 128) {
        const int c = d - 1;
        const int b = bid - 64;
        if (c >= 0 && c <= LASTC) {
            gemm_mfma_lds(smem, (c & 1) ? P.y0b : P.y0a, P.Wp1, P.b1, b);
            gru_body(smem, P.Bf1, P.b1, P.batch,
                     (c & 1) ? P.y1b : P.y1a, nullptr, 0, nullptr, P.h1,
                     c * TC, b);
        }
    } else {
        const int c = d - 2;
        const int b = bid - 128;
        if (c >= 0 && c <= LASTC) {
            gemm_mfma_lds(smem, (c & 1) ? P.y1b : P.y1a, P.Wp2, P.b2, b);
            gru_body(smem, P.Bf2, P.b2, P.batch,
                     nullptr, P.out, c * TC, (c == LASTC) ? P.hfin : nullptr,
                     P.h2, c * TC, b);
        }
    }
}

// ---------------------------------------------------------------------------
extern "C" void kernel_launch(void* const* d_in, const int* in_sizes, int n_in,
                              void* d_out, int out_size, void* d_ws, size_t ws_size,
                              hipStream_t stream)
{
    const int*   batch = (const int*)d_in[0];
    const float* W0 = (const float*)d_in[1];
    const float* U0 = (const float*)d_in[2];
    const float* b0 = (const float*)d_in[3];
    const float* W1 = (const float*)d_in[4];
    const float* U1 = (const float*)d_in[5];
    const float* b1 = (const float*)d_in[6];
    const float* W2 = (const float*)d_in[7];
    const float* U2 = (const float*)d_in[8];
    const float* b2 = (const float*)d_in[9];

    float* out  = (float*)d_out;
    float* hfin = out + (size_t)BATCH * SEQ * HID;

    const size_t YB  = (size_t)BATCH * TC * HID * 2;    // f16 y chunk bytes
    const size_t HB  = (size_t)BATCH * HID * 4;
    const size_t BFB = (size_t)48 * 8 * 64 * 4 * 4;     // packed-frag bytes

    char* p = (char*)d_ws;
    auto alloc = [&](size_t bytes) { char* q = p; p += (bytes + 255) & ~(size_t)255; return q; };
    _Float16* y0a  = (_Float16*)alloc(YB);
    _Float16* y0b  = (_Float16*)alloc(YB);
    _Float16* y1a  = (_Float16*)alloc(YB);
    _Float16* y1b  = (_Float16*)alloc(YB);
    float* h0  = (float*)alloc(HB);
    float* h1  = (float*)alloc(HB);
    float* h2  = (float*)alloc(HB);
    float* Bf0 = (float*)alloc(BFB);
    float* Bf1 = (float*)alloc(BFB);
    float* Bf2 = (float*)alloc(BFB);
    float* Wp1 = (float*)alloc(BFB);
    float* Wp2 = (float*)alloc(BFB);

    dim3 gpack(48 * 8 * 64 / 256), bpack(256);
    k_packB<<<gpack, bpack, 0, stream>>>(U0, Bf0);
    k_packB<<<gpack, bpack, 0, stream>>>(U1, Bf1);
    k_packB<<<gpack, bpack, 0, stream>>>(U2, Bf2);
    k_packB<<<gpack, bpack, 0, stream>>>(W1, Wp1);
    k_packB<<<gpack, bpack, 0, stream>>>(W2, Wp2);

    Params P;
    P.batch = batch;
    P.W0 = W0; P.b0 = b0; P.b1 = b1; P.b2 = b2;
    P.Bf0 = Bf0; P.Bf1 = Bf1; P.Bf2 = Bf2;
    P.Wp1 = Wp1; P.Wp2 = Wp2;
    P.y0a = y0a; P.y0b = y0b; P.y1a = y1a; P.y1b = y1b;
    P.h0 = h0; P.h1 = h1; P.h2 = h2;
    P.out = out; P.hfin = hfin;

    for (int d = 0; d <= LASTC + 2; ++d)
        k_fused<<<dim3(192), dim3(NT), 0, stream>>>(P, d);
}

// Round 18
// 1381.441 us; speedup vs baseline: 1.0593x; 1.0593x over previous
//
#include <hip/hip_runtime.h>
#include <cstdint>

#define BATCH 64
#define SEQ   1024
#define FEAT  16
#define HID   256
#define GATE  768    // 3*HID
#define TC    64     // time-chunk length
#define LASTC 15     // SEQ/TC - 1
#define NT    512    // block threads (8 waves)

typedef _Float16 f16x8 __attribute__((ext_vector_type(8)));
typedef float    f32x4 __attribute__((ext_vector_type(4)));

__device__ __forceinline__ float sigmoidf_(float x) { return 1.0f / (1.0f + __expf(-x)); }
__device__ __forceinline__ float tanhf_(float x)    { return 2.0f / (1.0f + __expf(-2.0f * x)) - 1.0f; }

// ---------------------------------------------------------------------------
// Pack a [HID][GATE] fp32 matrix (U or W1/W2) into MFMA B-fragments (f16).
// Fragment (ct, kt, lane): 8 f16 = M[kt*32 + (lane>>4)*8 + e][ct*16 + (lane&15)]
// at out[((ct*8 + kt)*64 + lane) * 4].  (Verified convention, rounds 5-17.)
// ---------------------------------------------------------------------------
__global__ __launch_bounds__(256) void k_packB(const float* __restrict__ U,
                                               float* __restrict__ Bfrag)
{
    const int tid = blockIdx.x * 256 + threadIdx.x;   // < 48*8*64
    const int ct   = tid >> 9;
    const int kt   = (tid >> 6) & 7;
    const int lane = tid & 63;
    const int g = lane >> 4, i = lane & 15;
    const int col = ct * 16 + i;
    const int k0  = kt * 32 + g * 8;
    union { f16x8 v; float4 f; } u;
#pragma unroll
    for (int e = 0; e < 8; ++e)
        u.v[e] = (_Float16)U[(size_t)(k0 + e) * GATE + col];
    *(float4*)(Bfrag + (size_t)tid * 4) = u.f;
}

// ---------------------------------------------------------------------------
struct Params {
    const int*   batch;
    const float *W0, *b0, *b1, *b2;
    const float *Bf0, *Bf1, *Bf2;   // packed U0,U1,U2
    const float *Wp1, *Wp2;         // packed W1,W2
    _Float16 *xp0a, *xp0b;          // f16 xp0 ring (cross-launch, parity)
    _Float16 *xp1, *xp2;            // f16 xp scratch (phase-private per block)
    _Float16 *y0a, *y0b, *y1a, *y1b;// f16 y rings (parity by chunk)
    float *h0, *h1, *h2;
    float *out, *hfin;
};

// ---------------------------------------------------------------------------
// GRU body: broadcast-A MFMA + 1-step xp prefetch + LDS-only barrier
// (lgkmcnt(0) + s_barrier) so the prefetched global loads stay in flight
// across the barrier. One block = ONE batch element; 8 waves; wave w owns
// h-cols [32w,32w+32).  (R11/R15/R16-verified, unchanged.)
// ---------------------------------------------------------------------------
__device__ __forceinline__ void gru_body(
    char* smem, const _Float16* __restrict__ xp, const float* __restrict__ Bfrag,
    const float* __restrict__ bb, const int* __restrict__ batch,
    _Float16* __restrict__ yout, float* __restrict__ fout, int obase,
    float* __restrict__ hfinal, float* __restrict__ hstate, int t0, int b)
{
    _Float16 (*hbuf)[HID] = (_Float16 (*)[HID])smem;   // [2][256] = 1 KB

    const int T  = threadIdx.x;
    const int w  = T >> 6;
    const int l  = T & 63;
    const int g  = l >> 4;
    const int i  = l & 15;
    const int g1 = g & 1;
    const int c  = 32 * w + i + 16 * g1;   // this lane's gate/h column

    // ---- register-resident B fragments: 6 col-tiles x 8 k-tiles ----
    f16x8 Bf[6][8];
    {
        const int cts[6] = {2 * w, 16 + 2 * w, 32 + 2 * w,
                            2 * w + 1, 17 + 2 * w, 33 + 2 * w};
#pragma unroll
        for (int ci = 0; ci < 6; ++ci)
#pragma unroll
            for (int kt = 0; kt < 8; ++kt) {
                float4 v = *(const float4*)(Bfrag + ((size_t)(cts[ci] * 8 + kt) * 64 + l) * 4);
                Bf[ci][kt] = __builtin_bit_cast(f16x8, v);
            }
    }

    const float bh = bb[GATE + 2 * HID + c];   // recurrent bias, h gate only

    float hprev = (t0 == 0) ? 0.0f : hstate[b * HID + c];
    if (l < 32) hbuf[0][32 * w + l] = (_Float16)hprev;

    // ---- prologue prefetch: step 0 xp + mask ----
    _Float16 nxz, nxr, nxh; int nmf;
    {
        const _Float16* xrow = xp + ((size_t)b * TC + 0) * GATE;
        nxz = xrow[c]; nxr = xrow[HID + c]; nxh = xrow[2 * HID + c];
        nmf = batch[((size_t)b * SEQ + t0) * FEAT + (FEAT - 1)];
    }
    __syncthreads();   // initial full barrier (once)

    for (int tl = 0; tl < TC; ++tl) {
        // consume prefetched values; immediately issue next step's loads
        const _Float16 cxz = nxz, cxr = nxr, cxh = nxh;
        const int cmf = nmf;
        {
            const int tn = (tl + 1 < TC) ? tl + 1 : tl;
            const _Float16* xrow = xp + ((size_t)b * TC + tn) * GATE;
            nxz = xrow[c]; nxr = xrow[HID + c]; nxh = xrow[2 * HID + c];
            nmf = batch[((size_t)b * SEQ + t0 + tn) * FEAT + (FEAT - 1)];
        }

        const _Float16* rd = hbuf[tl & 1];

        f32x4 az0 = {0.f, 0.f, 0.f, 0.f}, ar0 = az0, ah0 = az0;
        f32x4 az1 = az0, ar1 = az0, ah1 = az0;
#pragma unroll
        for (int kt = 0; kt < 8; ++kt) {
            const f16x8 a = *(const f16x8*)(rd + kt * 32 + g * 8);  // 16-lane broadcast
            az0 = __builtin_amdgcn_mfma_f32_16x16x32_f16(a, Bf[0][kt], az0, 0, 0, 0);
            ar0 = __builtin_amdgcn_mfma_f32_16x16x32_f16(a, Bf[1][kt], ar0, 0, 0, 0);
            ah0 = __builtin_amdgcn_mfma_f32_16x16x32_f16(a, Bf[2][kt], ah0, 0, 0, 0);
            az1 = __builtin_amdgcn_mfma_f32_16x16x32_f16(a, Bf[3][kt], az1, 0, 0, 0);
            ar1 = __builtin_amdgcn_mfma_f32_16x16x32_f16(a, Bf[4][kt], ar1, 0, 0, 0);
            ah1 = __builtin_amdgcn_mfma_f32_16x16x32_f16(a, Bf[5][kt], ah1, 0, 0, 0);
        }

        const float az = g1 ? az1[0] : az0[0];
        const float ar = g1 ? ar1[0] : ar0[0];
        const float ah = g1 ? ah1[0] : ah0[0];

        const float z  = sigmoidf_((float)cxz + az);
        const float r  = sigmoidf_((float)cxr + ar);
        const float hh = tanhf_((float)cxh + r * (ah + bh));
        float hn = z * hprev + (1.0f - z) * hh;
        hn = (cmf != -1) ? hn : hprev;
        hprev = hn;

        if (l < 32) {
            if (yout)
                yout[((size_t)b * TC + tl) * HID + 32 * w + l] = (_Float16)hn;
            else
                fout[((size_t)b * SEQ + obase + tl) * HID + 32 * w + l] = hn;
            hbuf[(tl & 1) ^ 1][32 * w + l] = (_Float16)hn;
        }
        // LDS-only barrier: prefetched global loads stay in flight
        asm volatile("s_waitcnt lgkmcnt(0)\n\ts_barrier" ::: "memory");
    }

    if (l < 32) {
        hstate[b * HID + 32 * w + l] = hprev;
        if (hfinal) hfinal[b * HID + 32 * w + l] = hprev;
    }
}

// ---------------------------------------------------------------------------
// MFMA GEMM body, full-N M-tile: xp[mt*64 .. +64][0..768) from Yc rows
// staged once in LDS. Wave w covers col-tiles ct = 6w..6w+5.
// Final __syncthreads (incl. vmcnt drain) orders the xp stores before any
// same-block consumer reads.  (R11/R16-verified, unchanged.)
// ---------------------------------------------------------------------------
__device__ __forceinline__ void gemm_mfma_body(
    char* smem, const _Float16* __restrict__ Yc, const float* __restrict__ Wp,
    const float* __restrict__ bb, _Float16* __restrict__ xpout, int mt)
{
    _Float16 (*As)[264] = (_Float16 (*)[264])smem;   // 64 x 264 (pad 8)

    const int T = threadIdx.x;
    const int w = T >> 6;
    const int l = T & 63;
    const int g = l >> 4;
    const int i = l & 15;

    {
        const _Float16* src = Yc + (size_t)mt * TC * HID;
#pragma unroll
        for (int q = 0; q < 4; ++q) {
            const int ch  = T * 4 + q;          // 0..2047 chunks of 16B
            const int row = ch >> 5;
            const int ko  = (ch & 31) * 8;
            *(float4*)&As[row][ko] = *(const float4*)(src + (size_t)row * HID + ko);
        }
    }
    __syncthreads();

    f16x8 Af[4][8];
#pragma unroll
    for (int rt = 0; rt < 4; ++rt)
#pragma unroll
        for (int kt = 0; kt < 8; ++kt)
            Af[rt][kt] = *(const f16x8*)&As[rt * 16 + i][kt * 32 + g * 8];

#pragma unroll
    for (int ci = 0; ci < 6; ++ci) {
        const int ct = w * 6 + ci;
        f16x8 Bfr[8];
#pragma unroll
        for (int kt = 0; kt < 8; ++kt) {
            float4 v = *(const float4*)(Wp + ((size_t)(ct * 8 + kt) * 64 + l) * 4);
            Bfr[kt] = __builtin_bit_cast(f16x8, v);
        }
        f32x4 acc[4];
#pragma unroll
        for (int rt = 0; rt < 4; ++rt) acc[rt] = (f32x4){0.f, 0.f, 0.f, 0.f};
#pragma unroll
        for (int kt = 0; kt < 8; ++kt) {
            acc[0] = __builtin_amdgcn_mfma_f32_16x16x32_f16(Af[0][kt], Bfr[kt], acc[0], 0, 0, 0);
            acc[1] = __builtin_amdgcn_mfma_f32_16x16x32_f16(Af[1][kt], Bfr[kt], acc[1], 0, 0, 0);
            acc[2] = __builtin_amdgcn_mfma_f32_16x16x32_f16(Af[2][kt], Bfr[kt], acc[2], 0, 0, 0);
            acc[3] = __builtin_amdgcn_mfma_f32_16x16x32_f16(Af[3][kt], Bfr[kt], acc[3], 0, 0, 0);
        }
        const int n = ct * 16 + i;
        const float bias = bb[n] + ((n < 2 * HID) ? bb[GATE + n] : 0.0f);
#pragma unroll
        for (int rt = 0; rt < 4; ++rt)
#pragma unroll
            for (int r = 0; r < 4; ++r)
                xpout[(size_t)(mt * TC + rt * 16 + 4 * g + r) * GATE + n] =
                    (_Float16)(acc[rt][r] + bias);
    }
    __syncthreads();   // drains stores (vmcnt) + frees As for hbuf reuse
}

// ---------------------------------------------------------------------------
// Layer-0 projection (unchanged from R11/R15/R16).
// ---------------------------------------------------------------------------
__device__ __forceinline__ void xp0_body(
    char* smem, const int* __restrict__ batch, const float* __restrict__ W0,
    const float* __restrict__ bb, _Float16* __restrict__ xpout, int t0, int b)
{
    int* bl = (int*)smem;   // [TC][FEAT] = 4KB
    const int T = threadIdx.x;
    for (int idx = T; idx < TC * FEAT; idx += NT)
        bl[idx] = batch[((size_t)b * SEQ + t0 + (idx >> 4)) * FEAT + (idx & 15)];
    __syncthreads();

    const int cc0 = T;            // 0..511
    const int cc1 = T + NT;       // 512..1023, valid if < GATE (T < 256)
    const bool two = (cc1 < GATE);

    float w0a[FEAT], w0b[FEAT];
#pragma unroll
    for (int f = 0; f < FEAT; ++f) w0a[f] = W0[f * GATE + cc0];
    if (two) {
#pragma unroll
        for (int f = 0; f < FEAT; ++f) w0b[f] = W0[f * GATE + cc1];
    }
    const float ba = bb[cc0] + ((cc0 < 2 * HID) ? bb[GATE + cc0] : 0.0f);
    const float bc = two ? (bb[cc1] + ((cc1 < 2 * HID) ? bb[GATE + cc1] : 0.0f)) : 0.0f;

    for (int tl = 0; tl < TC; ++tl) {
        float a0 = ba, a1 = bc;
#pragma unroll
        for (int f = 0; f < FEAT; ++f) {
            const float xf = (float)bl[tl * FEAT + f];   // LDS broadcast
            a0 += xf * w0a[f];
            if (two) a1 += xf * w0b[f];
        }
        _Float16* orow = xpout + ((size_t)b * TC + tl) * GATE;
        orow[cc0] = (_Float16)a0;
        if (two) orow[cc1] = (_Float16)a1;
    }
    __syncthreads();
}

// ---------------------------------------------------------------------------
// Fused pipeline kernel, EXACTLY 256 blocks (1 per CU), LAG-1 pipeline:
// the consumer gru block computes its own xp tile (inline gemm prologue)
// from the y ring written one phase earlier.
// Launch d (-1 .. LASTC+2):
//   bid   0- 63 : gru layer0 chunk d            (reads xp0 ring chunk d)
//   bid  64-127 : [gemm1(mt=b) from y0(d-1)] + gru layer1 chunk d-1
//   bid 128-191 : [gemm2(mt=b) from y1(d-2)] + gru layer2 chunk d-2
//   bid 192-255 : xp0 projection chunk d+1      (batch = bid-192)
// Ring parity: y0 written @ d&1, read @ (d-1)&1; y1 written @ (d-1)&1,
// read @ (d-2)&1 — always opposite within a phase. xp1/xp2 are
// phase-private (same block writes then reads; no cross-phase sharing).
// ---------------------------------------------------------------------------
__global__ __launch_bounds__(NT, 1) void k_fused(Params P, int d)
{
    __shared__ __align__(16) char smem[64 * 264 * 2];   // 33792 B (max of roles)
    const int bid = blockIdx.x;

    if (bid < 64) {
        const int c = d;
        if (c >= 0 && c <= LASTC)
            gru_body(smem, (c & 1) ? P.xp0b : P.xp0a, P.Bf0, P.b0, P.batch,
                     (c & 1) ? P.y0b : P.y0a, nullptr, 0, nullptr, P.h0,
                     c * TC, bid);
    } else if (bid < 128) {
        const int c = d - 1;
        const int b = bid - 64;
        if (c >= 0 && c <= LASTC) {
            gemm_mfma_body(smem, (c & 1) ? P.y0b : P.y0a, P.Wp1, P.b1, P.xp1, b);
            gru_body(smem, P.xp1, P.Bf1, P.b1, P.batch,
                     (c & 1) ? P.y1b : P.y1a, nullptr, 0, nullptr, P.h1,
                     c * TC, b);
        }
    } else if (bid < 192) {
        const int c = d - 2;
        const int b = bid - 128;
        if (c >= 0 && c <= LASTC) {
            gemm_mfma_body(smem, (c & 1) ? P.y1b : P.y1a, P.Wp2, P.b2, P.xp2, b);
            gru_body(smem, P.xp2, P.Bf2, P.b2, P.batch,
                     nullptr, P.out, c * TC, (c == LASTC) ? P.hfin : nullptr,
                     P.h2, c * TC, b);
        }
    } else {
        const int c = d + 1;
        if (c >= 0 && c <= LASTC)
            xp0_body(smem, P.batch, P.W0, P.b0,
                     (c & 1) ? P.xp0b : P.xp0a, c * TC, bid - 192);
    }
}

// ---------------------------------------------------------------------------
extern "C" void kernel_launch(void* const* d_in, const int* in_sizes, int n_in,
                              void* d_out, int out_size, void* d_ws, size_t ws_size,
                              hipStream_t stream)
{
    const int*   batch = (const int*)d_in[0];
    const float* W0 = (const float*)d_in[1];
    const float* U0 = (const float*)d_in[2];
    const float* b0 = (const float*)d_in[3];
    const float* W1 = (const float*)d_in[4];
    const float* U1 = (const float*)d_in[5];
    const float* b1 = (const float*)d_in[6];
    const float* W2 = (const float*)d_in[7];
    const float* U2 = (const float*)d_in[8];
    const float* b2 = (const float*)d_in[9];

    float* out  = (float*)d_out;
    float* hfin = out + (size_t)BATCH * SEQ * HID;

    const size_t XPB = (size_t)BATCH * TC * GATE * 2;   // f16 xp chunk bytes
    const size_t YB  = (size_t)BATCH * TC * HID * 2;    // f16 y chunk bytes
    const size_t HB  = (size_t)BATCH * HID * 4;
    const size_t BFB = (size_t)48 * 8 * 64 * 4 * 4;     // packed-frag bytes

    char* p = (char*)d_ws;
    auto alloc = [&](size_t bytes) { char* q = p; p += (bytes + 255) & ~(size_t)255; return q; };
    _Float16* xp0a = (_Float16*)alloc(XPB);
    _Float16* xp0b = (_Float16*)alloc(XPB);
    _Float16* xp1  = (_Float16*)alloc(XPB);
    _Float16* xp2  = (_Float16*)alloc(XPB);
    _Float16* y0a  = (_Float16*)alloc(YB);
    _Float16* y0b  = (_Float16*)alloc(YB);
    _Float16* y1a  = (_Float16*)alloc(YB);
    _Float16* y1b  = (_Float16*)alloc(YB);
    float* h0  = (float*)alloc(HB);
    float* h1  = (float*)alloc(HB);
    float* h2  = (float*)alloc(HB);
    float* Bf0 = (float*)alloc(BFB);
    float* Bf1 = (float*)alloc(BFB);
    float* Bf2 = (float*)alloc(BFB);
    float* Wp1 = (float*)alloc(BFB);
    float* Wp2 = (float*)alloc(BFB);

    dim3 gpack(48 * 8 * 64 / 256), bpack(256);
    k_packB<<<gpack, bpack, 0, stream>>>(U0, Bf0);
    k_packB<<<gpack, bpack, 0, stream>>>(U1, Bf1);
    k_packB<<<gpack, bpack, 0, stream>>>(U2, Bf2);
    k_packB<<<gpack, bpack, 0, stream>>>(W1, Wp1);
    k_packB<<<gpack, bpack, 0, stream>>>(W2, Wp2);

    Params P;
    P.batch = batch;
    P.W0 = W0; P.b0 = b0; P.b1 = b1; P.b2 = b2;
    P.Bf0 = Bf0; P.Bf1 = Bf1; P.Bf2 = Bf2;
    P.Wp1 = Wp1; P.Wp2 = Wp2;
    P.xp0a = xp0a; P.xp0b = xp0b;
    P.xp1 = xp1; P.xp2 = xp2;
    P.y0a = y0a; P.y0b = y0b; P.y1a = y1a; P.y1b = y1b;
    P.h0 = h0; P.h1 = h1; P.h2 = h2;
    P.out = out; P.hfin = hfin;

    for (int d = -1; d <= LASTC + 2; ++d)
        k_fused<<<dim3(256), dim3(NT), 0, stream>>>(P, d);
}